// Round 1
// baseline (439.273 us; speedup 1.0000x reference)
//
#include <hip/hip_runtime.h>

// VQ-VAE VectorQuantizer forward, fp32, MI355X.
// B=64, C=D=64, H=W=32 -> N=65536 pixels, K=1024 codes.
// Outputs (flat concat): [0] loss, [1..4194305) quantized BCHW, [4194305..) indices (as float)

#define KCODES 1024
#define DDIM   64
#define NPIX   65536        // B*H*W
#define QELEMS 4194304      // B*C*H*W
#define IDX_OFF (1 + QELEMS)

// ---------------- e_sq precompute: replicate np.sum(e*e, axis=1) pairwise-8 ----------------
__global__ void __launch_bounds__(256) esq_kernel(const float* __restrict__ e,
                                                  float* __restrict__ esq) {
    int k = blockIdx.x * 256 + threadIdx.x;
    if (k >= KCODES) return;
    {
#pragma clang fp contract(off)
        const float* row = e + k * DDIM;
        float r[8];
#pragma unroll
        for (int j = 0; j < 8; ++j) r[j] = row[j] * row[j];
#pragma unroll
        for (int i = 1; i < 8; ++i) {
#pragma unroll
            for (int j = 0; j < 8; ++j) {
                float v = row[i * 8 + j];
                r[j] += v * v;
            }
        }
        esq[k] = ((r[0] + r[1]) + (r[2] + r[3])) + ((r[4] + r[5]) + (r[6] + r[7]));
    }
}

// ---------------- main distance + argmin kernel ----------------
// 1 thread = 1 pixel. e-row loads are wave-uniform -> s_load (SGPR broadcast, no LDS).
// 4 codes interleaved -> 4 independent FMA chains for issue-rate at low occupancy.
__global__ void __launch_bounds__(256) argmin_kernel(const float* __restrict__ x,
                                                     const float* __restrict__ e,
                                                     const float* __restrict__ esq,
                                                     int* __restrict__ idx_out,
                                                     float* __restrict__ out) {
    const int i = blockIdx.x * 256 + threadIdx.x;   // pixel id
    const int b = i >> 10;
    const int p = i & 1023;

    // x[b][d][p], d-stride = 1024 floats; lanes -> consecutive p (coalesced)
    const float* xb = x + (size_t)b * 65536 + p;
    float xr[DDIM];
#pragma unroll
    for (int d = 0; d < DDIM; ++d) xr[d] = xb[(size_t)d * 1024];

    // x_sq: EXACT replication of numpy pairwise-8 (rounded products, no fp contraction)
    float xsq;
    {
#pragma clang fp contract(off)
        float r[8];
#pragma unroll
        for (int j = 0; j < 8; ++j) r[j] = xr[j] * xr[j];
#pragma unroll
        for (int ii = 1; ii < 8; ++ii) {
#pragma unroll
            for (int j = 0; j < 8; ++j) {
                float v = xr[ii * 8 + j];
                r[j] += v * v;
            }
        }
        xsq = ((r[0] + r[1]) + (r[2] + r[3])) + ((r[4] + r[5]) + (r[6] + r[7]));
    }

    float best = 3.4e38f;
    int bidx = 0;
    for (int k = 0; k < KCODES; k += 4) {
        const float* e0 = e + (size_t)k * DDIM;
        float d0 = 0.f, d1 = 0.f, d2 = 0.f, d3 = 0.f;
        // BLAS-style: sequential FMA chain over d ascending (one chain per code)
#pragma unroll
        for (int d = 0; d < DDIM; ++d) {
            float xv = xr[d];
            d0 = __builtin_fmaf(xv, e0[d], d0);
            d1 = __builtin_fmaf(xv, e0[64 + d], d1);
            d2 = __builtin_fmaf(xv, e0[128 + d], d2);
            d3 = __builtin_fmaf(xv, e0[192 + d], d3);
        }
        // dist = (x_sq - 2*dot) + e_sq   (same association as np; /64 exact-monotone, skipped)
        float s0 = (xsq - 2.0f * d0) + esq[k + 0];
        float s1 = (xsq - 2.0f * d1) + esq[k + 1];
        float s2 = (xsq - 2.0f * d2) + esq[k + 2];
        float s3 = (xsq - 2.0f * d3) + esq[k + 3];
        // strict < , ascending k  => first-occurrence min like np.argmin
        if (s0 < best) { best = s0; bidx = k + 0; }
        if (s1 < best) { best = s1; bidx = k + 1; }
        if (s2 < best) { best = s2; bidx = k + 2; }
        if (s3 < best) { best = s3; bidx = k + 3; }
    }
    idx_out[i] = bidx;
    out[IDX_OFF + i] = (float)bidx;   // harness reads d_out as float32
}

// ---------------- gather + transpose + per-block loss partials ----------------
// block = one (b,d) plane of 1024 pixels; coalesced read/write.
__global__ void __launch_bounds__(256) gather_kernel(const float* __restrict__ x,
                                                     const float* __restrict__ e,
                                                     const int* __restrict__ idx,
                                                     float* __restrict__ out,
                                                     float* __restrict__ partial) {
    const int bd = blockIdx.x;          // = b*64 + d
    const int b = bd >> 6;
    const int d = bd & 63;
    const size_t base = (size_t)bd * 1024;
    const int* idxb = idx + b * 1024;

    float acc = 0.f;
#pragma unroll
    for (int j = 0; j < 4; ++j) {
        int p = threadIdx.x + j * 256;
        int k = idxb[p];
        float ev = e[k * 64 + d];
        float xv = x[base + p];
        out[1 + base + p] = ev;         // quantized (straight-through == codebook value)
        float df = ev - xv;
        acc = __builtin_fmaf(df, df, acc);
    }
    __shared__ float sm[256];
    sm[threadIdx.x] = acc;
    __syncthreads();
    for (int s = 128; s > 0; s >>= 1) {
        if (threadIdx.x < s) sm[threadIdx.x] += sm[threadIdx.x + s];
        __syncthreads();
    }
    if (threadIdx.x == 0) partial[bd] = sm[0];
}

// ---------------- deterministic loss finalize ----------------
__global__ void __launch_bounds__(256) loss_kernel(const float* __restrict__ partial,
                                                   float* __restrict__ out) {
    float acc = 0.f;
    for (int i = threadIdx.x; i < 4096; i += 256) acc += partial[i];
    __shared__ float sm[256];
    sm[threadIdx.x] = acc;
    __syncthreads();
    for (int s = 128; s > 0; s >>= 1) {
        if (threadIdx.x < s) sm[threadIdx.x] += sm[threadIdx.x + s];
        __syncthreads();
    }
    // loss = q_latent + 0.25*e_latent = 1.25 * mean(diff^2)
    if (threadIdx.x == 0) out[0] = sm[0] * (1.25f / 4194304.f);
}

extern "C" void kernel_launch(void* const* d_in, const int* in_sizes, int n_in,
                              void* d_out, int out_size, void* d_ws, size_t ws_size,
                              hipStream_t stream) {
    const float* x = (const float*)d_in[0];   // [64,64,32,32]
    const float* e = (const float*)d_in[1];   // [1024,64]
    float* out = (float*)d_out;

    // ws: [0,4KB) e_sq | [4KB, 4KB+256KB) idx int32 | then 16KB partials
    float* esq = (float*)d_ws;
    int* idx = (int*)((char*)d_ws + 4096);
    float* partial = (float*)((char*)d_ws + 4096 + NPIX * 4);

    esq_kernel<<<4, 256, 0, stream>>>(e, esq);
    argmin_kernel<<<NPIX / 256, 256, 0, stream>>>(x, e, esq, idx, out);
    gather_kernel<<<4096, 256, 0, stream>>>(x, e, idx, out, partial);
    loss_kernel<<<1, 256, 0, stream>>>(partial, out);
}